// Round 4
// baseline (699.908 us; speedup 1.0000x reference)
//
#include <hip/hip_runtime.h>

#define L_TOT 10752
#define NF    256
#define BATCHN 4096
#define GRID  768

typedef __attribute__((ext_vector_type(8))) short short8;   // 8 bf16
typedef __attribute__((ext_vector_type(4))) float f32x4;

__device__ __forceinline__ unsigned short f2bf(float f) {
  unsigned int u = __float_as_uint(f);
  unsigned int r = (u + 0x7FFFu + ((u >> 16) & 1u)) >> 16;  // RNE
  return (unsigned short)r;
}

__device__ __forceinline__ float tanh_fast(float x) {
  float e2 = __builtin_amdgcn_exp2f(x * 2.8853900817779268f); // 2*log2(e)
  float r  = __builtin_amdgcn_rcpf(e2 + 1.0f);
  return fmaf(-2.0f, r, 1.0f);
}

// ---------------- schedules (R2/R3-verified reduction masks) ------------------
template<int G> struct Sch;
template<> struct Sch<0> {  // NC=6
  static constexpr int NT = 2, NC = 6;
  static constexpr int p6[2]  = {0b11, 0};
  static constexpr int m4[2]  = {0, 0b0011};
  static constexpr int m2a[2] = {0, 0b0100};
  static constexpr int m2b[2] = {0, 0b0100};
};
template<> struct Sch<1> {  // NC=9
  static constexpr int NT = 3, NC = 9;
  static constexpr int p6[3]  = {0b11, 0b01, 0};
  static constexpr int m4[3]  = {0, 0b1100, 0b0001};
  static constexpr int m2a[3] = {0, 0, 0b0110};
  static constexpr int m2b[3] = {0, 0, 0b0010};
};
template<> struct Sch<2> {  // NC=12
  static constexpr int NT = 4, NC = 12;
  static constexpr int p6[4]  = {0b11, 0b11, 0, 0};
  static constexpr int m4[4]  = {0, 0, 0b1111, 0};
  static constexpr int m2a[4] = {0, 0, 0, 0b0011};
  static constexpr int m2b[4] = {0, 0, 0, 0b0011};
};
template<> struct Sch<3> {  // NC=15
  static constexpr int NT = 5, NC = 15;
  static constexpr int p6[5]  = {0b11, 0b11, 0b01, 0, 0};
  static constexpr int m4[5]  = {0, 0, 0b1100, 0b0111, 0};
  static constexpr int m2a[5] = {0, 0, 0, 0b1000, 0b0011};
  static constexpr int m2b[5] = {0, 0, 0, 0b1000, 0b0001};
};

// ---------------- work-steal + grid barrier helpers ---------------------------
__device__ __forceinline__ int steal(unsigned* ctr, int* s_u) {
  __syncthreads();
  if (threadIdx.x == 0) *s_u = (int)atomicAdd(ctr, 1u);
  __syncthreads();
  return *s_u;
}

__device__ __forceinline__ void gbar(unsigned* c, unsigned n) {
  __syncthreads();                 // per-wave vmcnt(0): block's stores are in L2
  if (threadIdx.x == 0) {
    __hip_atomic_fetch_add(c, 1u, __ATOMIC_RELEASE, __HIP_MEMORY_SCOPE_AGENT);
    while (__hip_atomic_load(c, __ATOMIC_ACQUIRE, __HIP_MEMORY_SCOPE_AGENT) < n)
      __builtin_amdgcn_s_sleep(2);
  }
  __syncthreads();
  __threadfence();                 // acquire on EVERY thread (L1/L2 invalidate)
}

// ---------------- prep_w: masked transpose into padded row layout -------------
template<int G>
__device__ __forceinline__ void prep_w_body(
    const float* __restrict__ weight, const float* __restrict__ bias,
    const float* __restrict__ lm, int f, int ls, int fbase,
    unsigned short* __restrict__ WT, float* __restrict__ bias_p,
    unsigned short* s_t)
{
  using S = Sch<G>;
  constexpr int n3 = S::NC / 3;
  constexpr int LF = 12 * n3;
  constexpr int NROWS = S::NT * 16;
  const int tid = threadIdx.x;
  for (int e = tid; e < 128 * LF; e += 256) {
    int k = e / LF;
    int j = e - k * LF;
    float m = (fabsf(lm[k * NF + f]) > 1.0f) ? 1.0f : 0.0f;
    s_t[j * 136 + k] = f2bf(weight[(size_t)k * L_TOT + ls + j] * m);
  }
  __syncthreads();
  const int k = tid & 127, rb = tid >> 7;
  for (int R = rb; R < NROWS; R += 2) {
    int j = -1;
    if (R < 8 * n3)        { int dd = R & 7; if (dd < 6) j = 6 * n3 + 6 * (R >> 3) + dd; }
    else if (R < 12 * n3)  j = R - 6 * n3;
    else if (R < 14 * n3)  j = R - 12 * n3;
    unsigned short v = (j >= 0) ? s_t[j * 136 + k] : (unsigned short)0;
    WT[(size_t)(fbase + R) * 128 + k] = v;
    if (k == 0) bias_p[fbase + R] = (j >= 0) ? bias[ls + j] : 0.0f;
  }
}

// ---------------- dnnf pass: tiles [T0,T1), accumulates fs[iter] --------------
template<int G, int T0, int T1>
__device__ __forceinline__ void dnnf_pass(
    const unsigned short* __restrict__ A2,
    const unsigned short* __restrict__ WT,
    const float* __restrict__ bias_p,
    int fbase, int batch0, int wv, int n, int q, float* fs)
{
  using S = Sch<G>;
  constexpr int NP = T1 - T0;
  short8 wf[NP][4];
#pragma unroll
  for (int tt = 0; tt < NP; ++tt) {
    const unsigned short* wrow = WT + (size_t)(fbase + (T0 + tt) * 16 + n) * 128;
#pragma unroll
    for (int kk = 0; kk < 4; ++kk)
      wf[tt][kk] = *reinterpret_cast<const short8*>(wrow + kk * 32 + q * 8);
  }
  f32x4 brg[NP];
#pragma unroll
  for (int tt = 0; tt < NP; ++tt)
    brg[tt] = *reinterpret_cast<const f32x4*>(&bias_p[fbase + (T0 + tt) * 16 + q * 4]);

#pragma unroll
  for (int iter = 0; iter < 4; ++iter) {
    int brow = batch0 + iter * 64 + wv * 16;
    const unsigned short* xr = A2 + (size_t)(brow + n) * 256 + 128;
    short8 xa[4];
#pragma unroll
    for (int kk = 0; kk < 4; ++kk)
      xa[kk] = *reinterpret_cast<const short8*>(xr + kk * 32 + q * 8);

    f32x4 acc[NP];
#pragma unroll
    for (int tt = 0; tt < NP; ++tt) acc[tt] = (f32x4){0.f, 0.f, 0.f, 0.f};
#pragma unroll
    for (int kk = 0; kk < 4; ++kk)
#pragma unroll
      for (int tt = 0; tt < NP; ++tt)
        acc[tt] = __builtin_amdgcn_mfma_f32_16x16x32_bf16(wf[tt][kk], xa[kk], acc[tt], 0, 0, 0);

    float fsl = 0.0f;
#pragma unroll
    for (int tt = 0; tt < NP; ++tt) {
      const int t = T0 + tt;
      float v0 = tanh_fast(acc[tt][0] + brg[tt][0]);
      float v1 = tanh_fast(acc[tt][1] + brg[tt][1]);
      float v2 = tanh_fast(acc[tt][2] + brg[tt][2]);
      float v3 = tanh_fast(acc[tt][3] + brg[tt][3]);
      float s = v0 + v1 + v2 + v3;
      if (S::p6[t]) {
        float po = __shfl_xor(s, 16);
        float t6 = tanh_fast(s + po - 4.5f);
        bool add = ((q & 1) == 0) && ((S::p6[t] >> (q >> 1)) & 1);
        fsl += add ? t6 : 0.0f;
      }
      if (S::m4[t]) {
        float t4 = tanh_fast(s - 2.5f);
        fsl += ((S::m4[t] >> q) & 1) ? t4 : 0.0f;
      }
      if (S::m2a[t]) {
        float ta = tanh_fast(v0 + v1 - 0.5f);
        fsl += ((S::m2a[t] >> q) & 1) ? ta : 0.0f;
      }
      if (S::m2b[t]) {
        float tb = tanh_fast(v2 + v3 - 0.5f);
        fsl += ((S::m2b[t] >> q) & 1) ? tb : 0.0f;
      }
    }
    fs[iter] += fsl;
  }
}

template<int G>
__device__ __forceinline__ void dnnf_unit(
    const unsigned short* __restrict__ A2, const unsigned short* __restrict__ WT,
    const float* __restrict__ bias_p, float* __restrict__ dnnf_bf,
    int f, int fbase, int batch0)
{
  using S = Sch<G>;
  const int tid = threadIdx.x, lane = tid & 63, wv = tid >> 6;
  const int n = lane & 15, q = lane >> 4;
  float fs[4] = {0.f, 0.f, 0.f, 0.f};
  if constexpr (S::NT == 2)      dnnf_pass<G, 0, 2>(A2, WT, bias_p, fbase, batch0, wv, n, q, fs);
  else if constexpr (S::NT == 3) dnnf_pass<G, 0, 3>(A2, WT, bias_p, fbase, batch0, wv, n, q, fs);
  else if constexpr (S::NT == 4) {
    dnnf_pass<G, 0, 2>(A2, WT, bias_p, fbase, batch0, wv, n, q, fs);
    dnnf_pass<G, 2, 4>(A2, WT, bias_p, fbase, batch0, wv, n, q, fs);
  } else {
    dnnf_pass<G, 0, 3>(A2, WT, bias_p, fbase, batch0, wv, n, q, fs);
    dnnf_pass<G, 3, 5>(A2, WT, bias_p, fbase, batch0, wv, n, q, fs);
  }
#pragma unroll
  for (int iter = 0; iter < 4; ++iter) {
    float fsum = fs[iter];
    fsum += __shfl_xor(fsum, 16);
    fsum += __shfl_xor(fsum, 32);
    float dv = tanh_fast(fsum + (float)S::NC - 1.5f);
    int brow = batch0 + iter * 64 + wv * 16;
    if (lane < 16)
      dnnf_bf[(size_t)(brow + n) * NF + f] = dv;   // [b][f]: scatter-write, coalesced loc read
  }
}

// ---------------- loc unit: 8 batches x 256 formulas --------------------------
__device__ __forceinline__ void loc_unit(
    int u, const unsigned short* __restrict__ A2, const unsigned short* __restrict__ B2,
    const float* __restrict__ cf, const float* __restrict__ temp,
    const float* __restrict__ dnnf_bf, float* __restrict__ out, float (*s_part)[16])
{
  const int tid = threadIdx.x, lane = tid & 63, w = tid >> 6;
  const int n = lane & 15, q = lane >> 4;
  int b0 = u * 8;
  const unsigned short* arow = A2 + (size_t)(b0 + (n & 7)) * 256;  // rows 8-15 dup rows 0-7
  f32x4 acc[4];
#pragma unroll
  for (int t = 0; t < 4; ++t) acc[t] = (f32x4){0.f, 0.f, 0.f, 0.f};
#pragma unroll
  for (int kk = 0; kk < 8; ++kk) {
    short8 af = *reinterpret_cast<const short8*>(arow + kk * 32 + q * 8);
#pragma unroll
    for (int t = 0; t < 4; ++t) {
      const unsigned short* brow = B2 + (size_t)(w * 64 + t * 16 + n) * 256;
      short8 bf = *reinterpret_cast<const short8*>(brow + kk * 32 + q * 8);
      acc[t] = __builtin_amdgcn_mfma_f32_16x16x32_bf16(af, bf, acc[t], 0, 0, 0);
    }
  }
  float T = temp[0];
  float sg = 1.0f / (1.0f + __builtin_amdgcn_exp2f(-T * 1.4426950408889634f));
  float ez[4][4];
  float sr[4] = {0.f, 0.f, 0.f, 0.f};
#pragma unroll
  for (int t = 0; t < 4; ++t) {
    float c = cf[w * 64 + t * 16 + n];
#pragma unroll
    for (int r = 0; r < 4; ++r) {
      float n2 = fmaxf(acc[t][r] + c, 0.0f);
      float loc = __builtin_amdgcn_exp2f(-__builtin_amdgcn_sqrtf(n2) * 1.4426950408889634f);
      float e = __builtin_amdgcn_exp2f(sg * loc * 1.4426950408889634f);
      ez[t][r] = e;
      sr[r] += e;
    }
  }
#pragma unroll
  for (int o = 1; o < 16; o <<= 1)
#pragma unroll
    for (int r = 0; r < 4; ++r) sr[r] += __shfl_xor(sr[r], o);
  if (n == 0) {
#pragma unroll
    for (int r = 0; r < 4; ++r) s_part[w][q * 4 + r] = sr[r];
  }
  __syncthreads();
  float rtot[4];
#pragma unroll
  for (int r = 0; r < 4; ++r) {
    float tot = s_part[0][q * 4 + r] + s_part[1][q * 4 + r] +
                s_part[2][q * 4 + r] + s_part[3][q * 4 + r];
    rtot[r] = 1.0f / tot;
  }
  if (q < 2) {
#pragma unroll
    for (int t = 0; t < 4; ++t) {
      int fc = w * 64 + t * 16 + n;
#pragma unroll
      for (int r = 0; r < 4; ++r) {
        int bg = b0 + q * 4 + r;
        size_t idx = (size_t)bg * 256 + fc;
        out[idx] = dnnf_bf[idx] * ez[t][r] * rtot[r];
      }
    }
  }
}

// ---------------- the single persistent kernel --------------------------------
__global__ __launch_bounds__(256, 4) void fused_all(
    const float* __restrict__ x, const float* __restrict__ weight,
    const float* __restrict__ bias, const float* __restrict__ lm,
    const float* __restrict__ mu, const float* __restrict__ sigma,
    const float* __restrict__ temp,
    unsigned short* __restrict__ A2, unsigned short* __restrict__ B2,
    float* __restrict__ cf, unsigned short* __restrict__ WT,
    float* __restrict__ bias_p, float* __restrict__ dnnf_bf,
    float* __restrict__ out, unsigned* __restrict__ ctrs)
{
  __shared__ unsigned short s_t[60 * 136];
  __shared__ float s_part[4][16];
  __shared__ int s_u;
  const int tid = threadIdx.x;

  // ---- phase 0: all preps (units: 0-255 prep_w, 256-767 prep_x, 768-831 prep_b)
  for (;;) {
    int u = steal(&ctrs[0], &s_u);
    if (u >= 832) break;
    if (u < 256) {
      int f = u, g = f >> 6, fo = f & 63;
      if (g == 0)      prep_w_body<0>(weight, bias, lm, f, 0    + fo * 24, fo * 32,        WT, bias_p, s_t);
      else if (g == 1) prep_w_body<1>(weight, bias, lm, f, 1536 + fo * 36, 2048 + fo * 48, WT, bias_p, s_t);
      else if (g == 2) prep_w_body<2>(weight, bias, lm, f, 3840 + fo * 48, 5120 + fo * 64, WT, bias_p, s_t);
      else             prep_w_body<3>(weight, bias, lm, f, 6912 + fo * 60, 9216 + fo * 80, WT, bias_p, s_t);
    } else if (u < 768) {
      int i = (u - 256) * 256 + tid;          // 131072 float4s of x
      float4 v = ((const float4*)x)[i];
      int b = i >> 5, kc = i & 31;
      ushort4 sq, xx;
      sq.x = f2bf(v.x * v.x); sq.y = f2bf(v.y * v.y);
      sq.z = f2bf(v.z * v.z); sq.w = f2bf(v.w * v.w);
      xx.x = f2bf(v.x); xx.y = f2bf(v.y); xx.z = f2bf(v.z); xx.w = f2bf(v.w);
      ((ushort4*)A2)[b * 64 + kc] = sq;
      ((ushort4*)A2)[b * 64 + 32 + kc] = xx;
    } else {
      int f = (u - 768) * 4 + (tid >> 6);
      int k = tid & 63;
      float acc = 0.0f;
      for (int kk = k; kk < 128; kk += 64) {
        float s = sigma[f * 128 + kk], m = mu[f * 128 + kk];
        float s2 = s * s;
        B2[f * 256 + kk] = f2bf(s2);
        B2[f * 256 + 128 + kk] = f2bf(-2.0f * m * s2);
        acc = fmaf(m * m, s2, acc);
      }
      for (int o = 1; o < 64; o <<= 1) acc += __shfl_xor(acc, o);
      if (k == 0) cf[f] = acc;
    }
  }
  gbar(&ctrs[3], GRID);

  // ---- phase 1: dnnf (4096 units = formula x 256-batch chunk)
  for (;;) {
    int u = steal(&ctrs[1], &s_u);
    if (u >= 4096) break;
    int f = u >> 4, batch0 = (u & 15) * 256;
    int g = f >> 6, fo = f & 63;
    if (g == 0)      dnnf_unit<0>(A2, WT, bias_p, dnnf_bf, f, fo * 32,        batch0);
    else if (g == 1) dnnf_unit<1>(A2, WT, bias_p, dnnf_bf, f, 2048 + fo * 48, batch0);
    else if (g == 2) dnnf_unit<2>(A2, WT, bias_p, dnnf_bf, f, 5120 + fo * 64, batch0);
    else             dnnf_unit<3>(A2, WT, bias_p, dnnf_bf, f, 9216 + fo * 80, batch0);
  }
  gbar(&ctrs[4], GRID);

  // ---- phase 2: loc+softmax+mul (512 units of 8 batches)
  for (;;) {
    int u = steal(&ctrs[2], &s_u);
    if (u >= 512) break;
    loc_unit(u, A2, B2, cf, temp, dnnf_bf, out, s_part);
  }
}

extern "C" void kernel_launch(void* const* d_in, const int* in_sizes, int n_in,
                              void* d_out, int out_size, void* d_ws, size_t ws_size,
                              hipStream_t stream) {
  const float* x      = (const float*)d_in[0];
  const float* weight = (const float*)d_in[1];
  const float* bias   = (const float*)d_in[2];
  const float* lm     = (const float*)d_in[3];
  const float* mu     = (const float*)d_in[4];
  const float* sigma  = (const float*)d_in[5];
  const float* temp   = (const float*)d_in[6];
  float* out = (float*)d_out;

  char* ws = (char*)d_ws;
  unsigned short* A2      = (unsigned short*)(ws);                 // 2 MB
  float*          dnnf_bf = (float*)(ws + 2097152);                // 4 MB [b][f]
  unsigned short* B2      = (unsigned short*)(ws + 6291456);       // 128 KB
  float*          cf      = (float*)(ws + 6422528);                // 1 KB
  unsigned short* WT      = (unsigned short*)(ws + 6423552);       // 3.5 MB
  float*          bias_p  = (float*)(ws + 10093568);               // 56 KB
  unsigned*       ctrs    = (unsigned*)(ws + 10158080);            // 32 B counters

  hipMemsetAsync(ctrs, 0, 32, stream);
  fused_all<<<GRID, 256, 0, stream>>>(x, weight, bias, lm, mu, sigma, temp,
                                      A2, B2, cf, WT, bias_p, dnnf_bf, out, ctrs);
}

// Round 5
// 365.604 us; speedup vs baseline: 1.9144x; 1.9144x over previous
//
#include <hip/hip_runtime.h>

#define L_TOT 10752
#define NF    256
#define BATCHN 4096
#define GRID  768

typedef __attribute__((ext_vector_type(8))) short short8;   // 8 bf16
typedef __attribute__((ext_vector_type(4))) float f32x4;

__device__ __forceinline__ unsigned short f2bf(float f) {
  unsigned int u = __float_as_uint(f);
  unsigned int r = (u + 0x7FFFu + ((u >> 16) & 1u)) >> 16;  // RNE
  return (unsigned short)r;
}

__device__ __forceinline__ float tanh_fast(float x) {
  float e2 = __builtin_amdgcn_exp2f(x * 2.8853900817779268f); // 2*log2(e)
  float r  = __builtin_amdgcn_rcpf(e2 + 1.0f);
  return fmaf(-2.0f, r, 1.0f);
}

// ---------------- schedules (R2/R3/R4-verified reduction masks) ---------------
template<int G> struct Sch;
template<> struct Sch<0> {  // NC=6
  static constexpr int NT = 2, NC = 6;
  static constexpr int p6[2]  = {0b11, 0};
  static constexpr int m4[2]  = {0, 0b0011};
  static constexpr int m2a[2] = {0, 0b0100};
  static constexpr int m2b[2] = {0, 0b0100};
};
template<> struct Sch<1> {  // NC=9
  static constexpr int NT = 3, NC = 9;
  static constexpr int p6[3]  = {0b11, 0b01, 0};
  static constexpr int m4[3]  = {0, 0b1100, 0b0001};
  static constexpr int m2a[3] = {0, 0, 0b0110};
  static constexpr int m2b[3] = {0, 0, 0b0010};
};
template<> struct Sch<2> {  // NC=12
  static constexpr int NT = 4, NC = 12;
  static constexpr int p6[4]  = {0b11, 0b11, 0, 0};
  static constexpr int m4[4]  = {0, 0, 0b1111, 0};
  static constexpr int m2a[4] = {0, 0, 0, 0b0011};
  static constexpr int m2b[4] = {0, 0, 0, 0b0011};
};
template<> struct Sch<3> {  // NC=15
  static constexpr int NT = 5, NC = 15;
  static constexpr int p6[5]  = {0b11, 0b11, 0b01, 0, 0};
  static constexpr int m4[5]  = {0, 0, 0b1100, 0b0111, 0};
  static constexpr int m2a[5] = {0, 0, 0, 0b1000, 0b0011};
  static constexpr int m2b[5] = {0, 0, 0, 0b1000, 0b0001};
};

// ---------------- grid barrier: release add, RELAXED spin, one fence ----------
// Agent-scope ACQUIRE per poll invalidates the XCD L2 (R4: 700us). Relaxed
// atomic loads go to the coherence point without invalidation; the single
// __threadfence() after exit does one wbl2+inv per block per barrier.
__device__ __forceinline__ void gbar(unsigned* c, unsigned n) {
  __syncthreads();                 // all waves' stores issued + vmcnt(0)
  if (threadIdx.x == 0) {
    __hip_atomic_fetch_add(c, 1u, __ATOMIC_RELEASE, __HIP_MEMORY_SCOPE_AGENT);
    while (__hip_atomic_load(c, __ATOMIC_RELAXED, __HIP_MEMORY_SCOPE_AGENT) < n)
      __builtin_amdgcn_s_sleep(16);
  }
  __syncthreads();
  __threadfence();                 // acquire: invalidate stale L1/L2 once
}

// ---------------- prep_w: masked transpose into padded row layout -------------
template<int G>
__device__ __forceinline__ void prep_w_body(
    const float* __restrict__ weight, const float* __restrict__ bias,
    const float* __restrict__ lm, int f, int ls, int fbase,
    unsigned short* __restrict__ WT, float* __restrict__ bias_p,
    unsigned short* s_t)
{
  using S = Sch<G>;
  constexpr int n3 = S::NC / 3;
  constexpr int LF = 12 * n3;
  constexpr int NROWS = S::NT * 16;
  const int tid = threadIdx.x;
  for (int e = tid; e < 128 * LF; e += 256) {
    int k = e / LF;
    int j = e - k * LF;
    float m = (fabsf(lm[k * NF + f]) > 1.0f) ? 1.0f : 0.0f;
    s_t[j * 136 + k] = f2bf(weight[(size_t)k * L_TOT + ls + j] * m);
  }
  __syncthreads();
  const int k = tid & 127, rb = tid >> 7;
  for (int R = rb; R < NROWS; R += 2) {
    int j = -1;
    if (R < 8 * n3)        { int dd = R & 7; if (dd < 6) j = 6 * n3 + 6 * (R >> 3) + dd; }
    else if (R < 12 * n3)  j = R - 6 * n3;
    else if (R < 14 * n3)  j = R - 12 * n3;
    unsigned short v = (j >= 0) ? s_t[j * 136 + k] : (unsigned short)0;
    WT[(size_t)(fbase + R) * 128 + k] = v;
    if (k == 0) bias_p[fbase + R] = (j >= 0) ? bias[ls + j] : 0.0f;
  }
  __syncthreads();   // s_t reused only within this unit; blocks do one prep_w
}

// ---------------- dnnf pass: tiles [T0,T1), accumulates fs[iter] --------------
template<int G, int T0, int T1>
__device__ __forceinline__ void dnnf_pass(
    const unsigned short* __restrict__ A2,
    const unsigned short* __restrict__ WT,
    const float* __restrict__ bias_p,
    int fbase, int batch0, int wv, int n, int q, float* fs)
{
  using S = Sch<G>;
  constexpr int NP = T1 - T0;
  short8 wf[NP][4];
#pragma unroll
  for (int tt = 0; tt < NP; ++tt) {
    const unsigned short* wrow = WT + (size_t)(fbase + (T0 + tt) * 16 + n) * 128;
#pragma unroll
    for (int kk = 0; kk < 4; ++kk)
      wf[tt][kk] = *reinterpret_cast<const short8*>(wrow + kk * 32 + q * 8);
  }
  f32x4 brg[NP];
#pragma unroll
  for (int tt = 0; tt < NP; ++tt)
    brg[tt] = *reinterpret_cast<const f32x4*>(&bias_p[fbase + (T0 + tt) * 16 + q * 4]);

#pragma unroll
  for (int iter = 0; iter < 4; ++iter) {
    int brow = batch0 + iter * 64 + wv * 16;
    const unsigned short* xr = A2 + (size_t)(brow + n) * 256 + 128;
    short8 xa[4];
#pragma unroll
    for (int kk = 0; kk < 4; ++kk)
      xa[kk] = *reinterpret_cast<const short8*>(xr + kk * 32 + q * 8);

    f32x4 acc[NP];
#pragma unroll
    for (int tt = 0; tt < NP; ++tt) acc[tt] = (f32x4){0.f, 0.f, 0.f, 0.f};
#pragma unroll
    for (int kk = 0; kk < 4; ++kk)
#pragma unroll
      for (int tt = 0; tt < NP; ++tt)
        acc[tt] = __builtin_amdgcn_mfma_f32_16x16x32_bf16(wf[tt][kk], xa[kk], acc[tt], 0, 0, 0);

    float fsl = 0.0f;
#pragma unroll
    for (int tt = 0; tt < NP; ++tt) {
      const int t = T0 + tt;
      float v0 = tanh_fast(acc[tt][0] + brg[tt][0]);
      float v1 = tanh_fast(acc[tt][1] + brg[tt][1]);
      float v2 = tanh_fast(acc[tt][2] + brg[tt][2]);
      float v3 = tanh_fast(acc[tt][3] + brg[tt][3]);
      float s = v0 + v1 + v2 + v3;
      if (S::p6[t]) {
        float po = __shfl_xor(s, 16);
        float t6 = tanh_fast(s + po - 4.5f);
        bool add = ((q & 1) == 0) && ((S::p6[t] >> (q >> 1)) & 1);
        fsl += add ? t6 : 0.0f;
      }
      if (S::m4[t]) {
        float t4 = tanh_fast(s - 2.5f);
        fsl += ((S::m4[t] >> q) & 1) ? t4 : 0.0f;
      }
      if (S::m2a[t]) {
        float ta = tanh_fast(v0 + v1 - 0.5f);
        fsl += ((S::m2a[t] >> q) & 1) ? ta : 0.0f;
      }
      if (S::m2b[t]) {
        float tb = tanh_fast(v2 + v3 - 0.5f);
        fsl += ((S::m2b[t] >> q) & 1) ? tb : 0.0f;
      }
    }
    fs[iter] += fsl;
  }
}

template<int G>
__device__ __forceinline__ void dnnf_unit(
    const unsigned short* __restrict__ A2, const unsigned short* __restrict__ WT,
    const float* __restrict__ bias_p, float* __restrict__ dnnf_f,
    int f, int fbase, int batch0)
{
  using S = Sch<G>;
  const int tid = threadIdx.x, lane = tid & 63, wv = tid >> 6;
  const int n = lane & 15, q = lane >> 4;
  float fs[4] = {0.f, 0.f, 0.f, 0.f};
  if constexpr (S::NT == 2)      dnnf_pass<G, 0, 2>(A2, WT, bias_p, fbase, batch0, wv, n, q, fs);
  else if constexpr (S::NT == 3) dnnf_pass<G, 0, 3>(A2, WT, bias_p, fbase, batch0, wv, n, q, fs);
  else if constexpr (S::NT == 4) {
    dnnf_pass<G, 0, 2>(A2, WT, bias_p, fbase, batch0, wv, n, q, fs);
    dnnf_pass<G, 2, 4>(A2, WT, bias_p, fbase, batch0, wv, n, q, fs);
  } else {
    dnnf_pass<G, 0, 3>(A2, WT, bias_p, fbase, batch0, wv, n, q, fs);
    dnnf_pass<G, 3, 5>(A2, WT, bias_p, fbase, batch0, wv, n, q, fs);
  }
#pragma unroll
  for (int iter = 0; iter < 4; ++iter) {
    float fsum = fs[iter];
    fsum += __shfl_xor(fsum, 16);
    fsum += __shfl_xor(fsum, 32);
    float dv = tanh_fast(fsum + (float)S::NC - 1.5f);
    int brow = batch0 + iter * 64 + wv * 16;
    if (lane < 16)
      dnnf_f[(size_t)f * BATCHN + brow + n] = dv;   // [f][b]: coalesced 64B store
  }
}

// ---------------- loc unit: 8 batches x 256 formulas --------------------------
__device__ __forceinline__ void loc_unit(
    int u, const unsigned short* __restrict__ A2, const unsigned short* __restrict__ B2,
    const float* __restrict__ cf, const float* __restrict__ temp,
    const float* __restrict__ dnnf_f, float* __restrict__ out, float (*s_part)[16])
{
  const int tid = threadIdx.x, lane = tid & 63, w = tid >> 6;
  const int n = lane & 15, q = lane >> 4;
  int b0 = u * 8;
  const unsigned short* arow = A2 + (size_t)(b0 + (n & 7)) * 256;  // rows 8-15 dup 0-7
  f32x4 acc[4];
#pragma unroll
  for (int t = 0; t < 4; ++t) acc[t] = (f32x4){0.f, 0.f, 0.f, 0.f};
#pragma unroll
  for (int kk = 0; kk < 8; ++kk) {
    short8 af = *reinterpret_cast<const short8*>(arow + kk * 32 + q * 8);
#pragma unroll
    for (int t = 0; t < 4; ++t) {
      const unsigned short* brow = B2 + (size_t)(w * 64 + t * 16 + n) * 256;
      short8 bf = *reinterpret_cast<const short8*>(brow + kk * 32 + q * 8);
      acc[t] = __builtin_amdgcn_mfma_f32_16x16x32_bf16(af, bf, acc[t], 0, 0, 0);
    }
  }
  float T = temp[0];
  float sg = 1.0f / (1.0f + __builtin_amdgcn_exp2f(-T * 1.4426950408889634f));
  float ez[4][4];
  float sr[4] = {0.f, 0.f, 0.f, 0.f};
#pragma unroll
  for (int t = 0; t < 4; ++t) {
    float c = cf[w * 64 + t * 16 + n];
#pragma unroll
    for (int r = 0; r < 4; ++r) {
      float n2 = fmaxf(acc[t][r] + c, 0.0f);
      float loc = __builtin_amdgcn_exp2f(-__builtin_amdgcn_sqrtf(n2) * 1.4426950408889634f);
      float e = __builtin_amdgcn_exp2f(sg * loc * 1.4426950408889634f);
      ez[t][r] = e;
      sr[r] += e;
    }
  }
#pragma unroll
  for (int o = 1; o < 16; o <<= 1)
#pragma unroll
    for (int r = 0; r < 4; ++r) sr[r] += __shfl_xor(sr[r], o);
  if (n == 0) {
#pragma unroll
    for (int r = 0; r < 4; ++r) s_part[w][q * 4 + r] = sr[r];
  }
  __syncthreads();
  float rtot[4];
#pragma unroll
  for (int r = 0; r < 4; ++r) {
    float tot = s_part[0][q * 4 + r] + s_part[1][q * 4 + r] +
                s_part[2][q * 4 + r] + s_part[3][q * 4 + r];
    rtot[r] = 1.0f / tot;
  }
  if (q < 2) {
#pragma unroll
    for (int t = 0; t < 4; ++t) {
      int fc = w * 64 + t * 16 + n;
#pragma unroll
      for (int r = 0; r < 4; ++r) {
        int bg = b0 + q * 4 + r;
        out[(size_t)bg * 256 + fc] = dnnf_f[(size_t)fc * BATCHN + bg] * ez[t][r] * rtot[r];
      }
    }
  }
}

// ---------------- the single persistent kernel (static partition) -------------
__global__ __launch_bounds__(256, 4) void fused_all(
    const float* __restrict__ x, const float* __restrict__ weight,
    const float* __restrict__ bias, const float* __restrict__ lm,
    const float* __restrict__ mu, const float* __restrict__ sigma,
    const float* __restrict__ temp,
    unsigned short* __restrict__ A2, unsigned short* __restrict__ B2,
    float* __restrict__ cf, unsigned short* __restrict__ WT,
    float* __restrict__ bias_p, float* __restrict__ dnnf_f,
    float* __restrict__ out, unsigned* __restrict__ ctrs)
{
  __shared__ unsigned short s_t[60 * 136];
  __shared__ float s_part[4][16];
  const int tid = threadIdx.x;
  const int b = blockIdx.x;

  // ---- phase 0: preps, statically assigned
  if (b < 256) {
    int f = b, g = f >> 6, fo = f & 63;
    if (g == 0)      prep_w_body<0>(weight, bias, lm, f, 0    + fo * 24, fo * 32,        WT, bias_p, s_t);
    else if (g == 1) prep_w_body<1>(weight, bias, lm, f, 1536 + fo * 36, 2048 + fo * 48, WT, bias_p, s_t);
    else if (g == 2) prep_w_body<2>(weight, bias, lm, f, 3840 + fo * 48, 5120 + fo * 64, WT, bias_p, s_t);
    else             prep_w_body<3>(weight, bias, lm, f, 6912 + fo * 60, 9216 + fo * 80, WT, bias_p, s_t);
  } else {
    int i = (b - 256) * 256 + tid;            // 512 units cover 4096x32 float4s of x
    float4 v = ((const float4*)x)[i];
    int bb = i >> 5, kc = i & 31;
    ushort4 sq, xx;
    sq.x = f2bf(v.x * v.x); sq.y = f2bf(v.y * v.y);
    sq.z = f2bf(v.z * v.z); sq.w = f2bf(v.w * v.w);
    xx.x = f2bf(v.x); xx.y = f2bf(v.y); xx.z = f2bf(v.z); xx.w = f2bf(v.w);
    ((ushort4*)A2)[bb * 64 + kc] = sq;
    ((ushort4*)A2)[bb * 64 + 32 + kc] = xx;
  }
  if (b < 64) {                               // prep_b: 64 blocks x 4 formulas
    int f = b * 4 + (tid >> 6);
    int k = tid & 63;
    float acc = 0.0f;
    for (int kk = k; kk < 128; kk += 64) {
      float s = sigma[f * 128 + kk], m = mu[f * 128 + kk];
      float s2 = s * s;
      B2[f * 256 + kk] = f2bf(s2);
      B2[f * 256 + 128 + kk] = f2bf(-2.0f * m * s2);
      acc = fmaf(m * m, s2, acc);
    }
    for (int o = 1; o < 64; o <<= 1) acc += __shfl_xor(acc, o);
    if (k == 0) cf[f] = acc;
  }
  gbar(&ctrs[0], GRID);

  // ---- phase 1: dnnf, 4096 units static-strided (balanced group mix)
  for (int u = b; u < 4096; u += GRID) {
    int f = u >> 4, batch0 = (u & 15) * 256;
    int g = f >> 6, fo = f & 63;
    if (g == 0)      dnnf_unit<0>(A2, WT, bias_p, dnnf_f, f, fo * 32,        batch0);
    else if (g == 1) dnnf_unit<1>(A2, WT, bias_p, dnnf_f, f, 2048 + fo * 48, batch0);
    else if (g == 2) dnnf_unit<2>(A2, WT, bias_p, dnnf_f, f, 5120 + fo * 64, batch0);
    else             dnnf_unit<3>(A2, WT, bias_p, dnnf_f, f, 9216 + fo * 80, batch0);
  }
  gbar(&ctrs[1], GRID);

  // ---- phase 2: loc+softmax+mul, 512 units of 8 batches
  if (b < 512)
    loc_unit(b, A2, B2, cf, temp, dnnf_f, out, s_part);
}

extern "C" void kernel_launch(void* const* d_in, const int* in_sizes, int n_in,
                              void* d_out, int out_size, void* d_ws, size_t ws_size,
                              hipStream_t stream) {
  const float* x      = (const float*)d_in[0];
  const float* weight = (const float*)d_in[1];
  const float* bias   = (const float*)d_in[2];
  const float* lm     = (const float*)d_in[3];
  const float* mu     = (const float*)d_in[4];
  const float* sigma  = (const float*)d_in[5];
  const float* temp   = (const float*)d_in[6];
  float* out = (float*)d_out;

  char* ws = (char*)d_ws;
  unsigned short* A2      = (unsigned short*)(ws);                 // 2 MB
  float*          dnnf_f  = (float*)(ws + 2097152);                // 4 MB [f][b]
  unsigned short* B2      = (unsigned short*)(ws + 6291456);       // 128 KB
  float*          cf      = (float*)(ws + 6422528);                // 1 KB
  unsigned short* WT      = (unsigned short*)(ws + 6423552);       // 3.5 MB
  float*          bias_p  = (float*)(ws + 10093568);               // 56 KB
  unsigned*       ctrs    = (unsigned*)(ws + 10158080);            // barrier counters

  hipMemsetAsync(ctrs, 0, 32, stream);
  fused_all<<<GRID, 256, 0, stream>>>(x, weight, bias, lm, mu, sigma, temp,
                                      A2, B2, cf, WT, bias_p, dnnf_f, out, ctrs);
}

// Round 6
// 275.888 us; speedup vs baseline: 2.5369x; 1.3252x over previous
//
#include <hip/hip_runtime.h>

#define L_TOT 10752
#define NF    256
#define BATCHN 4096
#define GRID  512

typedef __attribute__((ext_vector_type(8))) short short8;   // 8 bf16
typedef __attribute__((ext_vector_type(4))) float f32x4;

__device__ __forceinline__ unsigned short f2bf(float f) {
  unsigned int u = __float_as_uint(f);
  unsigned int r = (u + 0x7FFFu + ((u >> 16) & 1u)) >> 16;  // RNE
  return (unsigned short)r;
}

__device__ __forceinline__ float tanh_fast(float x) {
  float e2 = __builtin_amdgcn_exp2f(x * 2.8853900817779268f); // 2*log2(e)
  float r  = __builtin_amdgcn_rcpf(e2 + 1.0f);
  return fmaf(-2.0f, r, 1.0f);
}

// ---------------- schedules (R2-R5-verified reduction masks) ------------------
template<int G> struct Sch;
template<> struct Sch<0> {  // NC=6
  static constexpr int NT = 2, NC = 6;
  static constexpr int p6[2]  = {0b11, 0};
  static constexpr int m4[2]  = {0, 0b0011};
  static constexpr int m2a[2] = {0, 0b0100};
  static constexpr int m2b[2] = {0, 0b0100};
};
template<> struct Sch<1> {  // NC=9
  static constexpr int NT = 3, NC = 9;
  static constexpr int p6[3]  = {0b11, 0b01, 0};
  static constexpr int m4[3]  = {0, 0b1100, 0b0001};
  static constexpr int m2a[3] = {0, 0, 0b0110};
  static constexpr int m2b[3] = {0, 0, 0b0010};
};
template<> struct Sch<2> {  // NC=12
  static constexpr int NT = 4, NC = 12;
  static constexpr int p6[4]  = {0b11, 0b11, 0, 0};
  static constexpr int m4[4]  = {0, 0, 0b1111, 0};
  static constexpr int m2a[4] = {0, 0, 0, 0b0011};
  static constexpr int m2b[4] = {0, 0, 0, 0b0011};
};
template<> struct Sch<3> {  // NC=15
  static constexpr int NT = 5, NC = 15;
  static constexpr int p6[5]  = {0b11, 0b11, 0b01, 0, 0};
  static constexpr int m4[5]  = {0, 0, 0b1100, 0b0111, 0};
  static constexpr int m2a[5] = {0, 0, 0, 0b1000, 0b0011};
  static constexpr int m2b[5] = {0, 0, 0, 0b1000, 0b0001};
};

// ---------------- grid barrier: release add, RELAXED spin, one fence ----------
__device__ __forceinline__ void gbar(unsigned* c, unsigned n) {
  __syncthreads();
  if (threadIdx.x == 0) {
    __hip_atomic_fetch_add(c, 1u, __ATOMIC_RELEASE, __HIP_MEMORY_SCOPE_AGENT);
    while (__hip_atomic_load(c, __ATOMIC_RELAXED, __HIP_MEMORY_SCOPE_AGENT) < n)
      __builtin_amdgcn_s_sleep(16);
  }
  __syncthreads();
  __threadfence();                 // one-time invalidate of stale L1/L2
}

// ---------------- prep_w: masked transpose into padded row layout -------------
template<int G>
__device__ __forceinline__ void prep_w_body(
    const float* __restrict__ weight, const float* __restrict__ bias,
    const float* __restrict__ lm, int f, int ls, int fbase,
    unsigned short* __restrict__ WT, float* __restrict__ bias_p,
    unsigned short* s_t)
{
  using S = Sch<G>;
  constexpr int n3 = S::NC / 3;
  constexpr int LF = 12 * n3;
  constexpr int NROWS = S::NT * 16;
  const int tid = threadIdx.x;
  for (int e = tid; e < 128 * LF; e += 256) {
    int k = e / LF;
    int j = e - k * LF;
    float m = (fabsf(lm[k * NF + f]) > 1.0f) ? 1.0f : 0.0f;
    s_t[j * 136 + k] = f2bf(weight[(size_t)k * L_TOT + ls + j] * m);
  }
  __syncthreads();
  const int k = tid & 127, rb = tid >> 7;
  for (int R = rb; R < NROWS; R += 2) {
    int j = -1;
    if (R < 8 * n3)        { int dd = R & 7; if (dd < 6) j = 6 * n3 + 6 * (R >> 3) + dd; }
    else if (R < 12 * n3)  j = R - 6 * n3;
    else if (R < 14 * n3)  j = R - 12 * n3;
    unsigned short v = (j >= 0) ? s_t[j * 136 + k] : (unsigned short)0;
    WT[(size_t)(fbase + R) * 128 + k] = v;
    if (k == 0) bias_p[fbase + R] = (j >= 0) ? bias[ls + j] : 0.0f;
  }
  __syncthreads();
}

// ---------------- dnnf pass: tiles [T0,T1), accumulates fs[iter] --------------
template<int G, int T0, int T1>
__device__ __forceinline__ void dnnf_pass(
    const unsigned short* __restrict__ A2,
    const unsigned short* __restrict__ WT,
    const float* __restrict__ bias_p,
    int fbase, int batch0, int wv, int n, int q, float* fs)
{
  using S = Sch<G>;
  constexpr int NP = T1 - T0;
  short8 wf[NP][4];
#pragma unroll
  for (int tt = 0; tt < NP; ++tt) {
    const unsigned short* wrow = WT + (size_t)(fbase + (T0 + tt) * 16 + n) * 128;
#pragma unroll
    for (int kk = 0; kk < 4; ++kk)
      wf[tt][kk] = *reinterpret_cast<const short8*>(wrow + kk * 32 + q * 8);
  }
  f32x4 brg[NP];
#pragma unroll
  for (int tt = 0; tt < NP; ++tt)
    brg[tt] = *reinterpret_cast<const f32x4*>(&bias_p[fbase + (T0 + tt) * 16 + q * 4]);

#pragma unroll
  for (int iter = 0; iter < 4; ++iter) {
    int brow = batch0 + iter * 64 + wv * 16;
    const unsigned short* xr = A2 + (size_t)(brow + n) * 256 + 128;
    short8 xa[4];
#pragma unroll
    for (int kk = 0; kk < 4; ++kk)
      xa[kk] = *reinterpret_cast<const short8*>(xr + kk * 32 + q * 8);

    f32x4 acc[NP];
#pragma unroll
    for (int tt = 0; tt < NP; ++tt) acc[tt] = (f32x4){0.f, 0.f, 0.f, 0.f};
#pragma unroll
    for (int kk = 0; kk < 4; ++kk)
#pragma unroll
      for (int tt = 0; tt < NP; ++tt)
        acc[tt] = __builtin_amdgcn_mfma_f32_16x16x32_bf16(wf[tt][kk], xa[kk], acc[tt], 0, 0, 0);

    float fsl = 0.0f;
#pragma unroll
    for (int tt = 0; tt < NP; ++tt) {
      const int t = T0 + tt;
      float v0 = tanh_fast(acc[tt][0] + brg[tt][0]);
      float v1 = tanh_fast(acc[tt][1] + brg[tt][1]);
      float v2 = tanh_fast(acc[tt][2] + brg[tt][2]);
      float v3 = tanh_fast(acc[tt][3] + brg[tt][3]);
      float s = v0 + v1 + v2 + v3;
      if (S::p6[t]) {
        float po = __shfl_xor(s, 16);
        float t6 = tanh_fast(s + po - 4.5f);
        bool add = ((q & 1) == 0) && ((S::p6[t] >> (q >> 1)) & 1);
        fsl += add ? t6 : 0.0f;
      }
      if (S::m4[t]) {
        float t4 = tanh_fast(s - 2.5f);
        fsl += ((S::m4[t] >> q) & 1) ? t4 : 0.0f;
      }
      if (S::m2a[t]) {
        float ta = tanh_fast(v0 + v1 - 0.5f);
        fsl += ((S::m2a[t] >> q) & 1) ? ta : 0.0f;
      }
      if (S::m2b[t]) {
        float tb = tanh_fast(v2 + v3 - 0.5f);
        fsl += ((S::m2b[t] >> q) & 1) ? tb : 0.0f;
      }
    }
    fs[iter] += fsl;
  }
}

template<int G>
__device__ __forceinline__ void dnnf_unit(
    const unsigned short* __restrict__ A2, const unsigned short* __restrict__ WT,
    const float* __restrict__ bias_p, float* __restrict__ dnnf_f,
    int f, int fbase, int batch0)
{
  using S = Sch<G>;
  const int tid = threadIdx.x, lane = tid & 63, wv = tid >> 6;
  const int n = lane & 15, q = lane >> 4;
  float fs[4] = {0.f, 0.f, 0.f, 0.f};
  if constexpr (S::NT == 2)      dnnf_pass<G, 0, 2>(A2, WT, bias_p, fbase, batch0, wv, n, q, fs);
  else if constexpr (S::NT == 3) dnnf_pass<G, 0, 3>(A2, WT, bias_p, fbase, batch0, wv, n, q, fs);
  else if constexpr (S::NT == 4) {
    dnnf_pass<G, 0, 2>(A2, WT, bias_p, fbase, batch0, wv, n, q, fs);
    dnnf_pass<G, 2, 4>(A2, WT, bias_p, fbase, batch0, wv, n, q, fs);
  } else {
    dnnf_pass<G, 0, 3>(A2, WT, bias_p, fbase, batch0, wv, n, q, fs);
    dnnf_pass<G, 3, 5>(A2, WT, bias_p, fbase, batch0, wv, n, q, fs);
  }
#pragma unroll
  for (int iter = 0; iter < 4; ++iter) {
    float fsum = fs[iter];
    fsum += __shfl_xor(fsum, 16);
    fsum += __shfl_xor(fsum, 32);
    float dv = tanh_fast(fsum + (float)S::NC - 1.5f);
    int brow = batch0 + iter * 64 + wv * 16;
    if (lane < 16)
      dnnf_f[(size_t)f * BATCHN + brow + n] = dv;   // [f][b]: coalesced 64B store
  }
}

// ---------------- loc unit: 8 batches x 256 formulas --------------------------
__device__ __forceinline__ void loc_unit(
    int u, const unsigned short* __restrict__ A2, const unsigned short* __restrict__ B2,
    const float* __restrict__ cf, const float* __restrict__ temp,
    const float* __restrict__ dnnf_f, float* __restrict__ out, float (*s_part)[16])
{
  const int tid = threadIdx.x, lane = tid & 63, w = tid >> 6;
  const int n = lane & 15, q = lane >> 4;
  int b0 = u * 8;
  const unsigned short* arow = A2 + (size_t)(b0 + (n & 7)) * 256;  // rows 8-15 dup 0-7
  f32x4 acc[4];
#pragma unroll
  for (int t = 0; t < 4; ++t) acc[t] = (f32x4){0.f, 0.f, 0.f, 0.f};
#pragma unroll
  for (int kk = 0; kk < 8; ++kk) {
    short8 af = *reinterpret_cast<const short8*>(arow + kk * 32 + q * 8);
#pragma unroll
    for (int t = 0; t < 4; ++t) {
      const unsigned short* brow = B2 + (size_t)(w * 64 + t * 16 + n) * 256;
      short8 bf = *reinterpret_cast<const short8*>(brow + kk * 32 + q * 8);
      acc[t] = __builtin_amdgcn_mfma_f32_16x16x32_bf16(af, bf, acc[t], 0, 0, 0);
    }
  }
  float T = temp[0];
  float sg = 1.0f / (1.0f + __builtin_amdgcn_exp2f(-T * 1.4426950408889634f));
  float ez[4][4];
  float sr[4] = {0.f, 0.f, 0.f, 0.f};
#pragma unroll
  for (int t = 0; t < 4; ++t) {
    float c = cf[w * 64 + t * 16 + n];
#pragma unroll
    for (int r = 0; r < 4; ++r) {
      float n2 = fmaxf(acc[t][r] + c, 0.0f);
      float loc = __builtin_amdgcn_exp2f(-__builtin_amdgcn_sqrtf(n2) * 1.4426950408889634f);
      float e = __builtin_amdgcn_exp2f(sg * loc * 1.4426950408889634f);
      ez[t][r] = e;
      sr[r] += e;
    }
  }
#pragma unroll
  for (int o = 1; o < 16; o <<= 1)
#pragma unroll
    for (int r = 0; r < 4; ++r) sr[r] += __shfl_xor(sr[r], o);
  if (n == 0) {
#pragma unroll
    for (int r = 0; r < 4; ++r) s_part[w][q * 4 + r] = sr[r];
  }
  __syncthreads();
  float rtot[4];
#pragma unroll
  for (int r = 0; r < 4; ++r) {
    float tot = s_part[0][q * 4 + r] + s_part[1][q * 4 + r] +
                s_part[2][q * 4 + r] + s_part[3][q * 4 + r];
    rtot[r] = 1.0f / tot;
  }
  if (q < 2) {
#pragma unroll
    for (int t = 0; t < 4; ++t) {
      int fc = w * 64 + t * 16 + n;
#pragma unroll
      for (int r = 0; r < 4; ++r) {
        int bg = b0 + q * 4 + r;
        out[(size_t)bg * 256 + fc] = dnnf_f[(size_t)fc * BATCHN + bg] * ez[t][r] * rtot[r];
      }
    }
  }
}

// ---------------- the single persistent kernel (512 blocks, no spills) --------
__global__ __launch_bounds__(256, 2) void fused_all(
    const float* __restrict__ x, const float* __restrict__ weight,
    const float* __restrict__ bias, const float* __restrict__ lm,
    const float* __restrict__ mu, const float* __restrict__ sigma,
    const float* __restrict__ temp,
    unsigned short* __restrict__ A2, unsigned short* __restrict__ B2,
    float* __restrict__ cf, unsigned short* __restrict__ WT,
    float* __restrict__ bias_p, float* __restrict__ dnnf_f,
    float* __restrict__ out, unsigned* __restrict__ ctrs)
{
  __shared__ unsigned short s_t[60 * 136];
  __shared__ float s_part[4][16];
  const int tid = threadIdx.x;
  const int b = blockIdx.x;

  // ---- phase 0: preps, statically assigned
  if (b < 256) {
    int f = b, g = f >> 6, fo = f & 63;
    if (g == 0)      prep_w_body<0>(weight, bias, lm, f, 0    + fo * 24, fo * 32,        WT, bias_p, s_t);
    else if (g == 1) prep_w_body<1>(weight, bias, lm, f, 1536 + fo * 36, 2048 + fo * 48, WT, bias_p, s_t);
    else if (g == 2) prep_w_body<2>(weight, bias, lm, f, 3840 + fo * 48, 5120 + fo * 64, WT, bias_p, s_t);
    else             prep_w_body<3>(weight, bias, lm, f, 6912 + fo * 60, 9216 + fo * 80, WT, bias_p, s_t);
  } else {
    // prep_x: 256 blocks x 512 float4s (2 per thread)
#pragma unroll
    for (int it = 0; it < 2; ++it) {
      int i = (b - 256) * 512 + it * 256 + tid;
      float4 v = ((const float4*)x)[i];
      int bb = i >> 5, kc = i & 31;
      ushort4 sq, xx;
      sq.x = f2bf(v.x * v.x); sq.y = f2bf(v.y * v.y);
      sq.z = f2bf(v.z * v.z); sq.w = f2bf(v.w * v.w);
      xx.x = f2bf(v.x); xx.y = f2bf(v.y); xx.z = f2bf(v.z); xx.w = f2bf(v.w);
      ((ushort4*)A2)[bb * 64 + kc] = sq;
      ((ushort4*)A2)[bb * 64 + 32 + kc] = xx;
    }
    if (b < 320) {                              // prep_b: 64 blocks x 4 formulas
      int f = (b - 256) * 4 + (tid >> 6);
      int k = tid & 63;
      float acc = 0.0f;
      for (int kk = k; kk < 128; kk += 64) {
        float s = sigma[f * 128 + kk], m = mu[f * 128 + kk];
        float s2 = s * s;
        B2[f * 256 + kk] = f2bf(s2);
        B2[f * 256 + 128 + kk] = f2bf(-2.0f * m * s2);
        acc = fmaf(m * m, s2, acc);
      }
      for (int o = 1; o < 64; o <<= 1) acc += __shfl_xor(acc, o);
      if (k == 0) cf[f] = acc;
    }
  }
  gbar(&ctrs[0], GRID);

  // ---- phase 1: dnnf, exactly 8 units per block (group-balanced)
  for (int u = b; u < 4096; u += GRID) {
    int f = u >> 4, batch0 = (u & 15) * 256;
    int g = f >> 6, fo = f & 63;
    if (g == 0)      dnnf_unit<0>(A2, WT, bias_p, dnnf_f, f, fo * 32,        batch0);
    else if (g == 1) dnnf_unit<1>(A2, WT, bias_p, dnnf_f, f, 2048 + fo * 48, batch0);
    else if (g == 2) dnnf_unit<2>(A2, WT, bias_p, dnnf_f, f, 5120 + fo * 64, batch0);
    else             dnnf_unit<3>(A2, WT, bias_p, dnnf_f, f, 9216 + fo * 80, batch0);
  }
  gbar(&ctrs[1], GRID);

  // ---- phase 2: loc+softmax+mul, 1 unit of 8 batches per block
  loc_unit(b, A2, B2, cf, temp, dnnf_f, out, s_part);
}

extern "C" void kernel_launch(void* const* d_in, const int* in_sizes, int n_in,
                              void* d_out, int out_size, void* d_ws, size_t ws_size,
                              hipStream_t stream) {
  const float* x      = (const float*)d_in[0];
  const float* weight = (const float*)d_in[1];
  const float* bias   = (const float*)d_in[2];
  const float* lm     = (const float*)d_in[3];
  const float* mu     = (const float*)d_in[4];
  const float* sigma  = (const float*)d_in[5];
  const float* temp   = (const float*)d_in[6];
  float* out = (float*)d_out;

  char* ws = (char*)d_ws;
  unsigned short* A2      = (unsigned short*)(ws);                 // 2 MB
  float*          dnnf_f  = (float*)(ws + 2097152);                // 4 MB [f][b]
  unsigned short* B2      = (unsigned short*)(ws + 6291456);       // 128 KB
  float*          cf      = (float*)(ws + 6422528);                // 1 KB
  unsigned short* WT      = (unsigned short*)(ws + 6423552);       // 3.5 MB
  float*          bias_p  = (float*)(ws + 10093568);               // 56 KB
  unsigned*       ctrs    = (unsigned*)(ws + 10158080);            // barrier counters

  hipMemsetAsync(ctrs, 0, 32, stream);
  fused_all<<<GRID, 256, 0, stream>>>(x, weight, bias, lm, mu, sigma, temp,
                                      A2, B2, cf, WT, bias_p, dnnf_f, out, ctrs);
}

// Round 7
// 188.102 us; speedup vs baseline: 3.7209x; 1.4667x over previous
//
#include <hip/hip_runtime.h>

#define L_TOT 10752
#define NF    256
#define BATCHN 4096

typedef __attribute__((ext_vector_type(8))) short short8;   // 8 bf16
typedef __attribute__((ext_vector_type(4))) float f32x4;

__device__ __forceinline__ unsigned short f2bf(float f) {
  unsigned int u = __float_as_uint(f);
  unsigned int r = (u + 0x7FFFu + ((u >> 16) & 1u)) >> 16;  // RNE
  return (unsigned short)r;
}

__device__ __forceinline__ float tanh_fast(float x) {
  float e2 = __builtin_amdgcn_exp2f(x * 2.8853900817779268f); // 2*log2(e)
  float r  = __builtin_amdgcn_rcpf(e2 + 1.0f);
  return fmaf(-2.0f, r, 1.0f);
}

// ---------------- schedules (R2-R6-verified reduction masks) ------------------
template<int G> struct Sch;
template<> struct Sch<0> {  // NC=6
  static constexpr int NT = 2, NC = 6;
  static constexpr int p6[2]  = {0b11, 0};
  static constexpr int m4[2]  = {0, 0b0011};
  static constexpr int m2a[2] = {0, 0b0100};
  static constexpr int m2b[2] = {0, 0b0100};
};
template<> struct Sch<1> {  // NC=9
  static constexpr int NT = 3, NC = 9;
  static constexpr int p6[3]  = {0b11, 0b01, 0};
  static constexpr int m4[3]  = {0, 0b1100, 0b0001};
  static constexpr int m2a[3] = {0, 0, 0b0110};
  static constexpr int m2b[3] = {0, 0, 0b0010};
};
template<> struct Sch<2> {  // NC=12
  static constexpr int NT = 4, NC = 12;
  static constexpr int p6[4]  = {0b11, 0b11, 0, 0};
  static constexpr int m4[4]  = {0, 0, 0b1111, 0};
  static constexpr int m2a[4] = {0, 0, 0, 0b0011};
  static constexpr int m2b[4] = {0, 0, 0, 0b0011};
};
template<> struct Sch<3> {  // NC=15
  static constexpr int NT = 5, NC = 15;
  static constexpr int p6[5]  = {0b11, 0b11, 0b01, 0, 0};
  static constexpr int m4[5]  = {0, 0, 0b1100, 0b0111, 0};
  static constexpr int m2a[5] = {0, 0, 0, 0b1000, 0b0011};
  static constexpr int m2b[5] = {0, 0, 0, 0b1000, 0b0001};
};

// ---------------- prep_w: masked transpose into padded row layout -------------
template<int G>
__device__ __forceinline__ void prep_w_body(
    const float* __restrict__ weight, const float* __restrict__ bias,
    const float* __restrict__ lm, int f, int ls, int fbase,
    unsigned short* __restrict__ WT, float* __restrict__ bias_p,
    unsigned short* s_t)
{
  using S = Sch<G>;
  constexpr int n3 = S::NC / 3;
  constexpr int LF = 12 * n3;
  constexpr int NROWS = S::NT * 16;
  const int tid = threadIdx.x;
  for (int e = tid; e < 128 * LF; e += 256) {
    int k = e / LF;
    int j = e - k * LF;
    float m = (fabsf(lm[k * NF + f]) > 1.0f) ? 1.0f : 0.0f;
    s_t[j * 136 + k] = f2bf(weight[(size_t)k * L_TOT + ls + j] * m);
  }
  __syncthreads();
  const int k = tid & 127, rb = tid >> 7;
  for (int R = rb; R < NROWS; R += 2) {
    int j = -1;
    if (R < 8 * n3)        { int dd = R & 7; if (dd < 6) j = 6 * n3 + 6 * (R >> 3) + dd; }
    else if (R < 12 * n3)  j = R - 6 * n3;
    else if (R < 14 * n3)  j = R - 12 * n3;
    unsigned short v = (j >= 0) ? s_t[j * 136 + k] : (unsigned short)0;
    WT[(size_t)(fbase + R) * 128 + k] = v;
    if (k == 0) bias_p[fbase + R] = (j >= 0) ? bias[ls + j] : 0.0f;
  }
}

// ---------------- prep_all: prep_w + prep_x + prep_b in one launch ------------
__global__ __launch_bounds__(256) void prep_all(
    const float* __restrict__ x, const float* __restrict__ weight,
    const float* __restrict__ bias, const float* __restrict__ lm,
    const float* __restrict__ mu, const float* __restrict__ sigma,
    unsigned short* __restrict__ A2, unsigned short* __restrict__ B2,
    float* __restrict__ cf, unsigned short* __restrict__ WT,
    float* __restrict__ bias_p)
{
  __shared__ unsigned short s_t[60 * 136];
  const int tid = threadIdx.x;
  const int b = blockIdx.x;
  if (b < 256) {
    int f = b, g = f >> 6, fo = f & 63;
    if (g == 0)      prep_w_body<0>(weight, bias, lm, f, 0    + fo * 24, fo * 32,        WT, bias_p, s_t);
    else if (g == 1) prep_w_body<1>(weight, bias, lm, f, 1536 + fo * 36, 2048 + fo * 48, WT, bias_p, s_t);
    else if (g == 2) prep_w_body<2>(weight, bias, lm, f, 3840 + fo * 48, 5120 + fo * 64, WT, bias_p, s_t);
    else             prep_w_body<3>(weight, bias, lm, f, 6912 + fo * 60, 9216 + fo * 80, WT, bias_p, s_t);
  } else {
#pragma unroll
    for (int it = 0; it < 2; ++it) {
      int i = (b - 256) * 512 + it * 256 + tid;   // 256 blocks cover 4096x32 float4s
      float4 v = ((const float4*)x)[i];
      int bb = i >> 5, kc = i & 31;
      ushort4 sq, xx;
      sq.x = f2bf(v.x * v.x); sq.y = f2bf(v.y * v.y);
      sq.z = f2bf(v.z * v.z); sq.w = f2bf(v.w * v.w);
      xx.x = f2bf(v.x); xx.y = f2bf(v.y); xx.z = f2bf(v.z); xx.w = f2bf(v.w);
      ((ushort4*)A2)[bb * 64 + kc] = sq;
      ((ushort4*)A2)[bb * 64 + 32 + kc] = xx;
    }
    if (b < 320) {                              // prep_b: 64 blocks x 4 formulas
      int f = (b - 256) * 4 + (tid >> 6);
      int k = tid & 63;
      float acc = 0.0f;
      for (int kk = k; kk < 128; kk += 64) {
        float s = sigma[f * 128 + kk], m = mu[f * 128 + kk];
        float s2 = s * s;
        B2[f * 256 + kk] = f2bf(s2);
        B2[f * 256 + 128 + kk] = f2bf(-2.0f * m * s2);
        acc = fmaf(m * m, s2, acc);
      }
      for (int o = 1; o < 64; o <<= 1) acc += __shfl_xor(acc, o);
      if (k == 0) cf[f] = acc;
    }
  }
}

// ---------------- dnnf pass: tiles [T0,T1), 2 batch iters ---------------------
template<int G, int T0, int T1>
__device__ __forceinline__ void dnnf_pass(
    const unsigned short* __restrict__ A2,
    const unsigned short* __restrict__ WT,
    const float* __restrict__ bias_p,
    int fbase, int batch0, int wv, int n, int q, float* fs)
{
  using S = Sch<G>;
  constexpr int NP = T1 - T0;
  short8 wf[NP][4];
#pragma unroll
  for (int tt = 0; tt < NP; ++tt) {
    const unsigned short* wrow = WT + (size_t)(fbase + (T0 + tt) * 16 + n) * 128;
#pragma unroll
    for (int kk = 0; kk < 4; ++kk)
      wf[tt][kk] = *reinterpret_cast<const short8*>(wrow + kk * 32 + q * 8);
  }
  f32x4 brg[NP];
#pragma unroll
  for (int tt = 0; tt < NP; ++tt)
    brg[tt] = *reinterpret_cast<const f32x4*>(&bias_p[fbase + (T0 + tt) * 16 + q * 4]);

#pragma unroll
  for (int iter = 0; iter < 2; ++iter) {
    int brow = batch0 + iter * 64 + wv * 16;
    const unsigned short* xr = A2 + (size_t)(brow + n) * 256 + 128;
    short8 xa[4];
#pragma unroll
    for (int kk = 0; kk < 4; ++kk)
      xa[kk] = *reinterpret_cast<const short8*>(xr + kk * 32 + q * 8);

    f32x4 acc[NP];
#pragma unroll
    for (int tt = 0; tt < NP; ++tt) acc[tt] = (f32x4){0.f, 0.f, 0.f, 0.f};
#pragma unroll
    for (int kk = 0; kk < 4; ++kk)
#pragma unroll
      for (int tt = 0; tt < NP; ++tt)
        acc[tt] = __builtin_amdgcn_mfma_f32_16x16x32_bf16(wf[tt][kk], xa[kk], acc[tt], 0, 0, 0);

    float fsl = 0.0f;
#pragma unroll
    for (int tt = 0; tt < NP; ++tt) {
      const int t = T0 + tt;
      float v0 = tanh_fast(acc[tt][0] + brg[tt][0]);
      float v1 = tanh_fast(acc[tt][1] + brg[tt][1]);
      float v2 = tanh_fast(acc[tt][2] + brg[tt][2]);
      float v3 = tanh_fast(acc[tt][3] + brg[tt][3]);
      float s = v0 + v1 + v2 + v3;
      if (S::p6[t]) {
        float po = __shfl_xor(s, 16);
        float t6 = tanh_fast(s + po - 4.5f);
        bool add = ((q & 1) == 0) && ((S::p6[t] >> (q >> 1)) & 1);
        fsl += add ? t6 : 0.0f;
      }
      if (S::m4[t]) {
        float t4 = tanh_fast(s - 2.5f);
        fsl += ((S::m4[t] >> q) & 1) ? t4 : 0.0f;
      }
      if (S::m2a[t]) {
        float ta = tanh_fast(v0 + v1 - 0.5f);
        fsl += ((S::m2a[t] >> q) & 1) ? ta : 0.0f;
      }
      if (S::m2b[t]) {
        float tb = tanh_fast(v2 + v3 - 0.5f);
        fsl += ((S::m2b[t] >> q) & 1) ? tb : 0.0f;
      }
    }
    fs[iter] += fsl;
  }
}

template<int G>
__device__ __forceinline__ void dnnf_unit(
    const unsigned short* __restrict__ A2, const unsigned short* __restrict__ WT,
    const float* __restrict__ bias_p, float* __restrict__ dnnf_f,
    int f, int fbase, int batch0)
{
  using S = Sch<G>;
  const int tid = threadIdx.x, lane = tid & 63, wv = tid >> 6;
  const int n = lane & 15, q = lane >> 4;
  float fs[2] = {0.f, 0.f};
  if constexpr (S::NT == 2)      dnnf_pass<G, 0, 2>(A2, WT, bias_p, fbase, batch0, wv, n, q, fs);
  else if constexpr (S::NT == 3) dnnf_pass<G, 0, 3>(A2, WT, bias_p, fbase, batch0, wv, n, q, fs);
  else if constexpr (S::NT == 4) {
    dnnf_pass<G, 0, 2>(A2, WT, bias_p, fbase, batch0, wv, n, q, fs);
    dnnf_pass<G, 2, 4>(A2, WT, bias_p, fbase, batch0, wv, n, q, fs);
  } else {
    dnnf_pass<G, 0, 3>(A2, WT, bias_p, fbase, batch0, wv, n, q, fs);
    dnnf_pass<G, 3, 5>(A2, WT, bias_p, fbase, batch0, wv, n, q, fs);
  }
#pragma unroll
  for (int iter = 0; iter < 2; ++iter) {
    float fsum = fs[iter];
    fsum += __shfl_xor(fsum, 16);
    fsum += __shfl_xor(fsum, 32);
    float dv = tanh_fast(fsum + (float)S::NC - 1.5f);
    int brow = batch0 + iter * 64 + wv * 16;
    if (lane < 16)
      dnnf_f[(size_t)f * BATCHN + brow + n] = dv;   // [f][b]: coalesced 64B store
  }
}

// 8192 blocks: f = bi>>5, 32 chunks of 128 batches -> 2x block parallelism vs R3
__global__ __launch_bounds__(256, 2) void dnnf_main(
    const unsigned short* __restrict__ A2,
    const unsigned short* __restrict__ WT,
    const float* __restrict__ bias_p,
    float* __restrict__ dnnf_f)
{
  int bi = blockIdx.x;
  int f = bi >> 5;
  int batch0 = (bi & 31) * 128;
  int g = f >> 6, fo = f & 63;
  if (g == 0)      dnnf_unit<0>(A2, WT, bias_p, dnnf_f, f, fo * 32,        batch0);
  else if (g == 1) dnnf_unit<1>(A2, WT, bias_p, dnnf_f, f, 2048 + fo * 48, batch0);
  else if (g == 2) dnnf_unit<2>(A2, WT, bias_p, dnnf_f, f, 5120 + fo * 64, batch0);
  else             dnnf_unit<3>(A2, WT, bias_p, dnnf_f, f, 9216 + fo * 80, batch0);
}

// ---------------- loc GEMM + softmax + multiply (8-batch units, f32x4 reads) --
__global__ __launch_bounds__(256) void loc_fused(
    const unsigned short* __restrict__ A2,   // [4096][256] bf16
    const unsigned short* __restrict__ B2,   // [256][256] bf16
    const float* __restrict__ cf,            // [256]
    const float* __restrict__ temp,
    const float* __restrict__ dnnf_f,        // [256][4096]
    float* __restrict__ out)                 // [4096][256]
{
  __shared__ float s_part[4][16];
  const int tid = threadIdx.x, lane = tid & 63, w = tid >> 6;
  const int n = lane & 15, q = lane >> 4;
  int b0 = blockIdx.x * 8;
  const unsigned short* arow = A2 + (size_t)(b0 + (n & 7)) * 256;  // rows 8-15 dup 0-7
  f32x4 acc[4];
#pragma unroll
  for (int t = 0; t < 4; ++t) acc[t] = (f32x4){0.f, 0.f, 0.f, 0.f};
#pragma unroll
  for (int kk = 0; kk < 8; ++kk) {
    short8 af = *reinterpret_cast<const short8*>(arow + kk * 32 + q * 8);
#pragma unroll
    for (int t = 0; t < 4; ++t) {
      const unsigned short* brow = B2 + (size_t)(w * 64 + t * 16 + n) * 256;
      short8 bf = *reinterpret_cast<const short8*>(brow + kk * 32 + q * 8);
      acc[t] = __builtin_amdgcn_mfma_f32_16x16x32_bf16(af, bf, acc[t], 0, 0, 0);
    }
  }
  float T = temp[0];
  float sg = 1.0f / (1.0f + __builtin_amdgcn_exp2f(-T * 1.4426950408889634f));
  float ez[4][4];
  float sr[4] = {0.f, 0.f, 0.f, 0.f};
#pragma unroll
  for (int t = 0; t < 4; ++t) {
    float c = cf[w * 64 + t * 16 + n];
#pragma unroll
    for (int r = 0; r < 4; ++r) {
      float n2 = fmaxf(acc[t][r] + c, 0.0f);
      float loc = __builtin_amdgcn_exp2f(-__builtin_amdgcn_sqrtf(n2) * 1.4426950408889634f);
      float e = __builtin_amdgcn_exp2f(sg * loc * 1.4426950408889634f);
      ez[t][r] = e;
      sr[r] += e;
    }
  }
#pragma unroll
  for (int o = 1; o < 16; o <<= 1)
#pragma unroll
    for (int r = 0; r < 4; ++r) sr[r] += __shfl_xor(sr[r], o);
  if (n == 0) {
#pragma unroll
    for (int r = 0; r < 4; ++r) s_part[w][q * 4 + r] = sr[r];
  }
  __syncthreads();
  float rtot[4];
#pragma unroll
  for (int r = 0; r < 4; ++r) {
    float tot = s_part[0][q * 4 + r] + s_part[1][q * 4 + r] +
                s_part[2][q * 4 + r] + s_part[3][q * 4 + r];
    rtot[r] = 1.0f / tot;
  }
  if (q < 2) {
#pragma unroll
    for (int t = 0; t < 4; ++t) {
      int fc = w * 64 + t * 16 + n;
      f32x4 dv4 = *reinterpret_cast<const f32x4*>(&dnnf_f[(size_t)fc * BATCHN + b0 + q * 4]);
#pragma unroll
      for (int r = 0; r < 4; ++r) {
        int bg = b0 + q * 4 + r;
        out[(size_t)bg * 256 + fc] = dv4[r] * ez[t][r] * rtot[r];
      }
    }
  }
}

extern "C" void kernel_launch(void* const* d_in, const int* in_sizes, int n_in,
                              void* d_out, int out_size, void* d_ws, size_t ws_size,
                              hipStream_t stream) {
  const float* x      = (const float*)d_in[0];
  const float* weight = (const float*)d_in[1];
  const float* bias   = (const float*)d_in[2];
  const float* lm     = (const float*)d_in[3];
  const float* mu     = (const float*)d_in[4];
  const float* sigma  = (const float*)d_in[5];
  const float* temp   = (const float*)d_in[6];
  float* out = (float*)d_out;

  char* ws = (char*)d_ws;
  unsigned short* A2      = (unsigned short*)(ws);                 // 2 MB
  float*          dnnf_f  = (float*)(ws + 2097152);                // 4 MB [f][b]
  unsigned short* B2      = (unsigned short*)(ws + 6291456);       // 128 KB
  float*          cf      = (float*)(ws + 6422528);                // 1 KB
  unsigned short* WT      = (unsigned short*)(ws + 6423552);       // 3.5 MB
  float*          bias_p  = (float*)(ws + 10093568);               // 56 KB

  prep_all<<<512, 256, 0, stream>>>(x, weight, bias, lm, mu, sigma,
                                    A2, B2, cf, WT, bias_p);
  dnnf_main<<<8192, 256, 0, stream>>>(A2, WT, bias_p, dnnf_f);
  loc_fused<<<512, 256, 0, stream>>>(A2, B2, cf, temp, dnnf_f, out);
}

// Round 8
// 176.281 us; speedup vs baseline: 3.9704x; 1.0671x over previous
//
#include <hip/hip_runtime.h>

#define L_TOT 10752
#define NF    256
#define BATCHN 4096
#define ITERS 8            // batch-iters per block: 512 batches/block, 2048 blocks

typedef __attribute__((ext_vector_type(8))) short short8;   // 8 bf16
typedef __attribute__((ext_vector_type(4))) float f32x4;

__device__ __forceinline__ unsigned short f2bf(float f) {
  unsigned int u = __float_as_uint(f);
  unsigned int r = (u + 0x7FFFu + ((u >> 16) & 1u)) >> 16;  // RNE
  return (unsigned short)r;
}

__device__ __forceinline__ float tanh_fast(float x) {
  float e2 = __builtin_amdgcn_exp2f(x * 2.8853900817779268f); // 2*log2(e)
  float r  = __builtin_amdgcn_rcpf(e2 + 1.0f);
  return fmaf(-2.0f, r, 1.0f);
}

// ---------------- schedules (R2-R7-verified reduction masks) ------------------
template<int G> struct Sch;
template<> struct Sch<0> {  // NC=6
  static constexpr int NT = 2, NC = 6;
  static constexpr int p6[2]  = {0b11, 0};
  static constexpr int m4[2]  = {0, 0b0011};
  static constexpr int m2a[2] = {0, 0b0100};
  static constexpr int m2b[2] = {0, 0b0100};
};
template<> struct Sch<1> {  // NC=9
  static constexpr int NT = 3, NC = 9;
  static constexpr int p6[3]  = {0b11, 0b01, 0};
  static constexpr int m4[3]  = {0, 0b1100, 0b0001};
  static constexpr int m2a[3] = {0, 0, 0b0110};
  static constexpr int m2b[3] = {0, 0, 0b0010};
};
template<> struct Sch<2> {  // NC=12
  static constexpr int NT = 4, NC = 12;
  static constexpr int p6[4]  = {0b11, 0b11, 0, 0};
  static constexpr int m4[4]  = {0, 0, 0b1111, 0};
  static constexpr int m2a[4] = {0, 0, 0, 0b0011};
  static constexpr int m2b[4] = {0, 0, 0, 0b0011};
};
template<> struct Sch<3> {  // NC=15
  static constexpr int NT = 5, NC = 15;
  static constexpr int p6[5]  = {0b11, 0b11, 0b01, 0, 0};
  static constexpr int m4[5]  = {0, 0, 0b1100, 0b0111, 0};
  static constexpr int m2a[5] = {0, 0, 0, 0b1000, 0b0011};
  static constexpr int m2b[5] = {0, 0, 0, 0b1000, 0b0001};
};

// ---------------- prep_w: masked transpose into padded row layout -------------
template<int G>
__device__ __forceinline__ void prep_w_body(
    const float* __restrict__ weight, const float* __restrict__ bias,
    const float* __restrict__ lm, int f, int ls, int fbase,
    unsigned short* __restrict__ WT, float* __restrict__ bias_p,
    unsigned short* s_t)
{
  using S = Sch<G>;
  constexpr int n3 = S::NC / 3;
  constexpr int LF = 12 * n3;
  constexpr int NROWS = S::NT * 16;
  const int tid = threadIdx.x;
  for (int e = tid; e < 128 * LF; e += 256) {
    int k = e / LF;
    int j = e - k * LF;
    float m = (fabsf(lm[k * NF + f]) > 1.0f) ? 1.0f : 0.0f;
    s_t[j * 136 + k] = f2bf(weight[(size_t)k * L_TOT + ls + j] * m);
  }
  __syncthreads();
  const int k = tid & 127, rb = tid >> 7;
  for (int R = rb; R < NROWS; R += 2) {
    int j = -1;
    if (R < 8 * n3)        { int dd = R & 7; if (dd < 6) j = 6 * n3 + 6 * (R >> 3) + dd; }
    else if (R < 12 * n3)  j = R - 6 * n3;
    else if (R < 14 * n3)  j = R - 12 * n3;
    unsigned short v = (j >= 0) ? s_t[j * 136 + k] : (unsigned short)0;
    WT[(size_t)(fbase + R) * 128 + k] = v;
    if (k == 0) bias_p[fbase + R] = (j >= 0) ? bias[ls + j] : 0.0f;
  }
}

// ---------------- prep_all: prep_w + prep_x + prep_b in one launch ------------
__global__ __launch_bounds__(256) void prep_all(
    const float* __restrict__ x, const float* __restrict__ weight,
    const float* __restrict__ bias, const float* __restrict__ lm,
    const float* __restrict__ mu, const float* __restrict__ sigma,
    unsigned short* __restrict__ A2, unsigned short* __restrict__ B2,
    float* __restrict__ cf, unsigned short* __restrict__ WT,
    float* __restrict__ bias_p)
{
  __shared__ unsigned short s_t[60 * 136];
  const int tid = threadIdx.x;
  const int b = blockIdx.x;
  if (b < 256) {
    int f = b, g = f >> 6, fo = f & 63;
    if (g == 0)      prep_w_body<0>(weight, bias, lm, f, 0    + fo * 24, fo * 32,        WT, bias_p, s_t);
    else if (g == 1) prep_w_body<1>(weight, bias, lm, f, 1536 + fo * 36, 2048 + fo * 48, WT, bias_p, s_t);
    else if (g == 2) prep_w_body<2>(weight, bias, lm, f, 3840 + fo * 48, 5120 + fo * 64, WT, bias_p, s_t);
    else             prep_w_body<3>(weight, bias, lm, f, 6912 + fo * 60, 9216 + fo * 80, WT, bias_p, s_t);
  } else {
#pragma unroll
    for (int it = 0; it < 2; ++it) {
      int i = (b - 256) * 512 + it * 256 + tid;   // 256 blocks cover 4096x32 float4s
      float4 v = ((const float4*)x)[i];
      int bb = i >> 5, kc = i & 31;
      ushort4 sq, xx;
      sq.x = f2bf(v.x * v.x); sq.y = f2bf(v.y * v.y);
      sq.z = f2bf(v.z * v.z); sq.w = f2bf(v.w * v.w);
      xx.x = f2bf(v.x); xx.y = f2bf(v.y); xx.z = f2bf(v.z); xx.w = f2bf(v.w);
      ((ushort4*)A2)[bb * 64 + kc] = sq;
      ((ushort4*)A2)[bb * 64 + 32 + kc] = xx;
    }
    if (b < 320) {                              // prep_b: 64 blocks x 4 formulas
      int f = (b - 256) * 4 + (tid >> 6);
      int k = tid & 63;
      float acc = 0.0f;
      for (int kk = k; kk < 128; kk += 64) {
        float s = sigma[f * 128 + kk], m = mu[f * 128 + kk];
        float s2 = s * s;
        B2[f * 256 + kk] = f2bf(s2);
        B2[f * 256 + 128 + kk] = f2bf(-2.0f * m * s2);
        acc = fmaf(m * m, s2, acc);
      }
      for (int o = 1; o < 64; o <<= 1) acc += __shfl_xor(acc, o);
      if (k == 0) cf[f] = acc;
    }
  }
}

// ---------------- dnnf pass: tiles [T0,T1), ITERS batch iters -----------------
template<int G, int T0, int T1>
__device__ __forceinline__ void dnnf_pass(
    const unsigned short* __restrict__ A2,
    const unsigned short* __restrict__ WT,
    const float* __restrict__ bias_p,
    int fbase, int batch0, int wv, int n, int q, float* fs)
{
  using S = Sch<G>;
  constexpr int NP = T1 - T0;
  short8 wf[NP][4];
#pragma unroll
  for (int tt = 0; tt < NP; ++tt) {
    const unsigned short* wrow = WT + (size_t)(fbase + (T0 + tt) * 16 + n) * 128;
#pragma unroll
    for (int kk = 0; kk < 4; ++kk)
      wf[tt][kk] = *reinterpret_cast<const short8*>(wrow + kk * 32 + q * 8);
  }
  f32x4 brg[NP];
#pragma unroll
  for (int tt = 0; tt < NP; ++tt)
    brg[tt] = *reinterpret_cast<const f32x4*>(&bias_p[fbase + (T0 + tt) * 16 + q * 4]);

#pragma unroll 2
  for (int iter = 0; iter < ITERS; ++iter) {
    int brow = batch0 + iter * 64 + wv * 16;
    const unsigned short* xr = A2 + (size_t)(brow + n) * 256 + 128;
    short8 xa[4];
#pragma unroll
    for (int kk = 0; kk < 4; ++kk)
      xa[kk] = *reinterpret_cast<const short8*>(xr + kk * 32 + q * 8);

    f32x4 acc[NP];
#pragma unroll
    for (int tt = 0; tt < NP; ++tt) acc[tt] = (f32x4){0.f, 0.f, 0.f, 0.f};
#pragma unroll
    for (int kk = 0; kk < 4; ++kk)
#pragma unroll
      for (int tt = 0; tt < NP; ++tt)
        acc[tt] = __builtin_amdgcn_mfma_f32_16x16x32_bf16(wf[tt][kk], xa[kk], acc[tt], 0, 0, 0);

    float fsl = 0.0f;
#pragma unroll
    for (int tt = 0; tt < NP; ++tt) {
      const int t = T0 + tt;
      float v0 = tanh_fast(acc[tt][0] + brg[tt][0]);
      float v1 = tanh_fast(acc[tt][1] + brg[tt][1]);
      float v2 = tanh_fast(acc[tt][2] + brg[tt][2]);
      float v3 = tanh_fast(acc[tt][3] + brg[tt][3]);
      float s = v0 + v1 + v2 + v3;
      if (S::p6[t]) {
        float po = __shfl_xor(s, 16);
        float t6 = tanh_fast(s + po - 4.5f);
        bool add = ((q & 1) == 0) && ((S::p6[t] >> (q >> 1)) & 1);
        fsl += add ? t6 : 0.0f;
      }
      if (S::m4[t]) {
        float t4 = tanh_fast(s - 2.5f);
        fsl += ((S::m4[t] >> q) & 1) ? t4 : 0.0f;
      }
      if (S::m2a[t]) {
        float ta = tanh_fast(v0 + v1 - 0.5f);
        fsl += ((S::m2a[t] >> q) & 1) ? ta : 0.0f;
      }
      if (S::m2b[t]) {
        float tb = tanh_fast(v2 + v3 - 0.5f);
        fsl += ((S::m2b[t] >> q) & 1) ? tb : 0.0f;
      }
    }
    fs[iter] += fsl;
  }
}

template<int G>
__device__ __forceinline__ void dnnf_unit(
    const unsigned short* __restrict__ A2, const unsigned short* __restrict__ WT,
    const float* __restrict__ bias_p, float* __restrict__ dnnf_f,
    int f, int fbase, int batch0)
{
  using S = Sch<G>;
  const int tid = threadIdx.x, lane = tid & 63, wv = tid >> 6;
  const int n = lane & 15, q = lane >> 4;
  float fs[ITERS];
#pragma unroll
  for (int i = 0; i < ITERS; ++i) fs[i] = 0.0f;
  if constexpr (S::NT == 2)      dnnf_pass<G, 0, 2>(A2, WT, bias_p, fbase, batch0, wv, n, q, fs);
  else if constexpr (S::NT == 3) dnnf_pass<G, 0, 3>(A2, WT, bias_p, fbase, batch0, wv, n, q, fs);
  else if constexpr (S::NT == 4) {
    dnnf_pass<G, 0, 2>(A2, WT, bias_p, fbase, batch0, wv, n, q, fs);
    dnnf_pass<G, 2, 4>(A2, WT, bias_p, fbase, batch0, wv, n, q, fs);
  } else {
    dnnf_pass<G, 0, 3>(A2, WT, bias_p, fbase, batch0, wv, n, q, fs);
    dnnf_pass<G, 3, 5>(A2, WT, bias_p, fbase, batch0, wv, n, q, fs);
  }
#pragma unroll
  for (int iter = 0; iter < ITERS; ++iter) {
    float fsum = fs[iter];
    fsum += __shfl_xor(fsum, 16);
    fsum += __shfl_xor(fsum, 32);
    float dv = tanh_fast(fsum + (float)S::NC - 1.5f);
    int brow = batch0 + iter * 64 + wv * 16;
    if (lane < 16)
      dnnf_f[(size_t)f * BATCHN + brow + n] = dv;   // [f][b]: coalesced 64B store
  }
}

// 2048 blocks: f = bi&255 (group-interleaved), 8 chunks of 512 batches
__global__ __launch_bounds__(256, 2) void dnnf_main(
    const unsigned short* __restrict__ A2,
    const unsigned short* __restrict__ WT,
    const float* __restrict__ bias_p,
    float* __restrict__ dnnf_f)
{
  int bi = blockIdx.x;
  int f = bi & 255;
  int batch0 = (bi >> 8) * (ITERS * 64);
  int g = f >> 6, fo = f & 63;
  if (g == 0)      dnnf_unit<0>(A2, WT, bias_p, dnnf_f, f, fo * 32,        batch0);
  else if (g == 1) dnnf_unit<1>(A2, WT, bias_p, dnnf_f, f, 2048 + fo * 48, batch0);
  else if (g == 2) dnnf_unit<2>(A2, WT, bias_p, dnnf_f, f, 5120 + fo * 64, batch0);
  else             dnnf_unit<3>(A2, WT, bias_p, dnnf_f, f, 9216 + fo * 80, batch0);
}

// ---------------- loc GEMM + softmax + multiply (8-batch units, f32x4 reads) --
__global__ __launch_bounds__(256) void loc_fused(
    const unsigned short* __restrict__ A2,   // [4096][256] bf16
    const unsigned short* __restrict__ B2,   // [256][256] bf16
    const float* __restrict__ cf,            // [256]
    const float* __restrict__ temp,
    const float* __restrict__ dnnf_f,        // [256][4096]
    float* __restrict__ out)                 // [4096][256]
{
  __shared__ float s_part[4][16];
  const int tid = threadIdx.x, lane = tid & 63, w = tid >> 6;
  const int n = lane & 15, q = lane >> 4;
  int b0 = blockIdx.x * 8;
  const unsigned short* arow = A2 + (size_t)(b0 + (n & 7)) * 256;  // rows 8-15 dup 0-7
  f32x4 acc[4];
#pragma unroll
  for (int t = 0; t < 4; ++t) acc[t] = (f32x4){0.f, 0.f, 0.f, 0.f};
#pragma unroll
  for (int kk = 0; kk < 8; ++kk) {
    short8 af = *reinterpret_cast<const short8*>(arow + kk * 32 + q * 8);
#pragma unroll
    for (int t = 0; t < 4; ++t) {
      const unsigned short* brow = B2 + (size_t)(w * 64 + t * 16 + n) * 256;
      short8 bf = *reinterpret_cast<const short8*>(brow + kk * 32 + q * 8);
      acc[t] = __builtin_amdgcn_mfma_f32_16x16x32_bf16(af, bf, acc[t], 0, 0, 0);
    }
  }
  float T = temp[0];
  float sg = 1.0f / (1.0f + __builtin_amdgcn_exp2f(-T * 1.4426950408889634f));
  float ez[4][4];
  float sr[4] = {0.f, 0.f, 0.f, 0.f};
#pragma unroll
  for (int t = 0; t < 4; ++t) {
    float c = cf[w * 64 + t * 16 + n];
#pragma unroll
    for (int r = 0; r < 4; ++r) {
      float n2 = fmaxf(acc[t][r] + c, 0.0f);
      float loc = __builtin_amdgcn_exp2f(-__builtin_amdgcn_sqrtf(n2) * 1.4426950408889634f);
      float e = __builtin_amdgcn_exp2f(sg * loc * 1.4426950408889634f);
      ez[t][r] = e;
      sr[r] += e;
    }
  }
#pragma unroll
  for (int o = 1; o < 16; o <<= 1)
#pragma unroll
    for (int r = 0; r < 4; ++r) sr[r] += __shfl_xor(sr[r], o);
  if (n == 0) {
#pragma unroll
    for (int r = 0; r < 4; ++r) s_part[w][q * 4 + r] = sr[r];
  }
  __syncthreads();
  float rtot[4];
#pragma unroll
  for (int r = 0; r < 4; ++r) {
    float tot = s_part[0][q * 4 + r] + s_part[1][q * 4 + r] +
                s_part[2][q * 4 + r] + s_part[3][q * 4 + r];
    rtot[r] = 1.0f / tot;
  }
  if (q < 2) {
#pragma unroll
    for (int t = 0; t < 4; ++t) {
      int fc = w * 64 + t * 16 + n;
      f32x4 dv4 = *reinterpret_cast<const f32x4*>(&dnnf_f[(size_t)fc * BATCHN + b0 + q * 4]);
#pragma unroll
      for (int r = 0; r < 4; ++r) {
        int bg = b0 + q * 4 + r;
        out[(size_t)bg * 256 + fc] = dv4[r] * ez[t][r] * rtot[r];
      }
    }
  }
}

extern "C" void kernel_launch(void* const* d_in, const int* in_sizes, int n_in,
                              void* d_out, int out_size, void* d_ws, size_t ws_size,
                              hipStream_t stream) {
  const float* x      = (const float*)d_in[0];
  const float* weight = (const float*)d_in[1];
  const float* bias   = (const float*)d_in[2];
  const float* lm     = (const float*)d_in[3];
  const float* mu     = (const float*)d_in[4];
  const float* sigma  = (const float*)d_in[5];
  const float* temp   = (const float*)d_in[6];
  float* out = (float*)d_out;

  char* ws = (char*)d_ws;
  unsigned short* A2      = (unsigned short*)(ws);                 // 2 MB
  float*          dnnf_f  = (float*)(ws + 2097152);                // 4 MB [f][b]
  unsigned short* B2      = (unsigned short*)(ws + 6291456);       // 128 KB
  float*          cf      = (float*)(ws + 6422528);                // 1 KB
  unsigned short* WT      = (unsigned short*)(ws + 6423552);       // 3.5 MB
  float*          bias_p  = (float*)(ws + 10093568);               // 56 KB

  prep_all<<<512, 256, 0, stream>>>(x, weight, bias, lm, mu, sigma,
                                    A2, B2, cf, WT, bias_p);
  dnnf_main<<<2048, 256, 0, stream>>>(A2, WT, bias_p, dnnf_f);
  loc_fused<<<512, 256, 0, stream>>>(A2, B2, cf, temp, dnnf_f, out);
}